// Round 6
// baseline (70.476 us; speedup 1.0000x reference)
//
#include <hip/hip_runtime.h>
#include <math.h>

#define B_ROWS 8192
#define D_DIM 64
#define C_DIM 16
#define NBLK1 128
#define ROWS_PER_BLK 64    // 8192 / NBLK1
#define CHUNK 16

// ws layout (floats):
//   pH    : NBLK1 * 4096  = 524288
//   pA    : NBLK1 * 1024  = 131072
//   pR    : NBLK1 * 1024  = 131072
//   invn  : 8192
//   W     : 1024
//   Hfull : 4096
//   Afull : 1024
//   Rfull : 1024
#define WS_PH    0
#define WS_PA    524288
#define WS_PR    655360
#define WS_INVN  786432
#define WS_W     794624
#define WS_HF    795648
#define WS_AF    799744
#define WS_RF    800768

__global__ __launch_bounds__(256) void lp_k1(const float* __restrict__ F,
        const int* __restrict__ lab, const int* __restrict__ mask,
        float* __restrict__ pH, float* __restrict__ pA, float* __restrict__ pR,
        float* __restrict__ invn)
{
    __shared__ float cJ[ROWS_PER_BLK];                    // mask_j * (1/||f_j||)
    __shared__ __align__(16) float fbuf[CHUNK][D_DIM];
    __shared__ __align__(16) float labf[CHUNK][C_DIM];
    __shared__ float mflag[CHUNK];
    const int t = threadIdx.x;
    const int row0 = blockIdx.x * ROWS_PER_BLK;

    // phase 1: row norms (threads 0..63, one row each)
    if (t < ROWS_PER_BLK) {
        const float4* fr = (const float4*)(F + (size_t)(row0 + t) * D_DIM);
        float ss = 0.0f;
        #pragma unroll
        for (int q = 0; q < 16; ++q) {
            float4 v = fr[q];
            ss += v.x*v.x + v.y*v.y + v.z*v.z + v.w*v.w;
        }
        float iv = 1.0f / sqrtf(ss);
        invn[row0 + t] = iv;
        cJ[t] = mask[row0 + t] ? iv : 0.0f;
    }
    __syncthreads();

    // phase 2: accumulate partial H (64x64), A (64x16), r0 (64x16)
    float h[16];
    float aacc[4], racc[4];
    #pragma unroll
    for (int k = 0; k < 16; ++k) h[k] = 0.0f;
    #pragma unroll
    for (int j = 0; j < 4; ++j) { aacc[j] = 0.0f; racc[j] = 0.0f; }

    const int d1  = t >> 2;          // H row owned by this thread
    const int d2b = (t & 3) << 4;    // H col block base (16 cols)
    const int cb  = (t & 3) << 2;    // label quad base (4 cols)

    for (int ch = 0; ch < ROWS_PER_BLK / CHUNK; ++ch) {
        // stage F chunk: 256 float4, one per thread, fully coalesced
        ((float4*)fbuf)[t] =
            ((const float4*)(F + (size_t)(row0 + ch*CHUNK) * D_DIM))[t];
        // stage labels: 256 ints, one per thread
        ((float*)labf)[t] = (float)lab[(size_t)(row0 + ch*CHUNK) * C_DIM + t];
        if (t < CHUNK) mflag[t] = mask[row0 + ch*CHUNK + t] ? 1.0f : 0.0f;
        __syncthreads();

        #pragma unroll
        for (int r = 0; r < CHUNK; ++r) {
            const float coef = cJ[ch*CHUNK + r];      // uniform -> broadcast
            const float fraw = fbuf[r][d1];           // 16 distinct words -> no conflict
            const float fd1  = fraw * coef;
            const float4* frow = (const float4*)(&fbuf[r][d2b]);
            const float4 f0 = frow[0], f1 = frow[1], f2 = frow[2], f3 = frow[3];
            h[ 0] += fd1 * f0.x; h[ 1] += fd1 * f0.y; h[ 2] += fd1 * f0.z; h[ 3] += fd1 * f0.w;
            h[ 4] += fd1 * f1.x; h[ 5] += fd1 * f1.y; h[ 6] += fd1 * f1.z; h[ 7] += fd1 * f1.w;
            h[ 8] += fd1 * f2.x; h[ 9] += fd1 * f2.y; h[10] += fd1 * f2.z; h[11] += fd1 * f2.w;
            h[12] += fd1 * f3.x; h[13] += fd1 * f3.y; h[14] += fd1 * f3.z; h[15] += fd1 * f3.w;

            const float mf = mflag[r];                // uniform -> broadcast
            const float fm = fraw * mf;               // masked row coefficient
            const float fn = fraw - fm;               // (1-m) coefficient (m in {0,1} -> exact)
            const float4 lv = *(const float4*)(&labf[r][cb]);
            aacc[0] += fn * lv.x; aacc[1] += fn * lv.y; aacc[2] += fn * lv.z; aacc[3] += fn * lv.w;
            racc[0] += fm * lv.x; racc[1] += fm * lv.y; racc[2] += fm * lv.z; racc[3] += fm * lv.w;
        }
        __syncthreads();
    }

    // store layout: (t>>2)*64+(t&3)*16+k == t*16+k
    #pragma unroll
    for (int k = 0; k < 16; ++k)
        pH[(size_t)blockIdx.x * 4096 + t*16 + k] = h[k];
    #pragma unroll
    for (int j = 0; j < 4; ++j) {
        pA[(size_t)blockIdx.x * 1024 + t*4 + j] = aacc[j];
        pR[(size_t)blockIdx.x * 1024 + t*4 + j] = racc[j];
    }
}

// reduce the per-block partials -> Hfull (4096), Afull (1024), Rfull (1024)
// coalesced: thread e strides over b; fixed b order -> deterministic sums
__global__ __launch_bounds__(256) void lp_k1b(const float* __restrict__ pH,
        const float* __restrict__ pA, const float* __restrict__ pR,
        float* __restrict__ Hf, float* __restrict__ Af, float* __restrict__ Rf)
{
    const int e = blockIdx.x * 256 + threadIdx.x;   // 0..6143
    if (e < 4096) {
        float s = 0.0f;
        for (int b = 0; b < NBLK1; ++b) s += pH[(size_t)b * 4096 + e];
        Hf[e] = s;
    } else if (e < 5120) {
        const int i = e - 4096;
        float s = 0.0f;
        for (int b = 0; b < NBLK1; ++b) s += pA[(size_t)b * 1024 + i];
        Af[i] = s;
    } else {
        const int i = e - 5120;
        float s = 0.0f;
        for (int b = 0; b < NBLK1; ++b) s += pR[(size_t)b * 1024 + i];
        Rf[i] = s;
    }
}

// 16 independent column evolutions: block c, ONE wave, lane = d.
// H row in 64 VGPRs. Per iter: 1 ds_write + fence + 16 HOISTED uniform
// ds_read_b128 (independent, broadcast, issued as one batch so their
// latency overlaps) + 64 FMA. No cross-wave barriers (single wave).
__global__ __launch_bounds__(64) void lp_k2(const float* __restrict__ Hf,
        const float* __restrict__ Af, const float* __restrict__ Rf,
        float* __restrict__ Wout)
{
    __shared__ __align__(16) float gs[64];
    const int d = threadIdx.x;   // 0..63
    const int c = blockIdx.x;    // 0..15

    float4 hq[16];
    const float4* Hrow = (const float4*)(Hf + d * 64);
    #pragma unroll
    for (int q = 0; q < 16; ++q) hq[q] = Hrow[q];

    const float a = Af[d * 16 + c];
    float r = Rf[d * 16 + c];

    float w = 0.0f;
    float g = r;                 // g_0 = r_0 (no +a on iteration 0)
    #pragma unroll 1
    for (int it = 0; it < 100; ++it) {
        w = 0.9f * w + 0.1f * g;
        gs[d] = g;
        __syncthreads();         // 1-wave block: compiles to lgkmcnt fence

        float4 gq[16];           // hoisted batch: 16 independent b128 loads
        #pragma unroll
        for (int q = 0; q < 16; ++q)
            gq[q] = ((const float4*)gs)[q];     // uniform addr -> broadcast

        float acc0 = 0.f, acc1 = 0.f, acc2 = 0.f, acc3 = 0.f;
        #pragma unroll
        for (int q = 0; q < 16; ++q) {
            acc0 += hq[q].x * gq[q].x;
            acc1 += hq[q].y * gq[q].y;
            acc2 += hq[q].z * gq[q].z;
            acc3 += hq[q].w * gq[q].w;
        }
        r = 0.9f * r + 0.1f * ((acc0 + acc1) + (acc2 + acc3));
        g = r + a;               // g for next iteration (it>=1 includes +a)
    }
    Wout[d * 16 + c] = w;
}

// one row per thread; q-loop NOT unrolled so only one 64-float Ws slice is
// live per scheduling region (prevents load-clustering -> VGPR spill)
__global__ __launch_bounds__(64) void lp_k3(const float* __restrict__ F,
        const int* __restrict__ lab, const int* __restrict__ mask,
        const float* __restrict__ invn, const float* __restrict__ Win,
        float* __restrict__ out)
{
    __shared__ __align__(16) float Ws[1024];   // [64][16] row-major
    const int t = threadIdx.x;                 // 0..63
    #pragma unroll
    for (int j = 0; j < 4; ++j)
        ((float4*)Ws)[j * 64 + t] = ((const float4*)Win)[j * 64 + t];
    __syncthreads();

    const int row = blockIdx.x * 64 + t;
    const float4* fr = (const float4*)(F + (size_t)row * D_DIM);

    float acc[16];
    #pragma unroll
    for (int c = 0; c < 16; ++c) acc[c] = 0.0f;

    #pragma unroll 1
    for (int q = 0; q < 16; ++q) {
        float4 v = fr[q];
        #pragma unroll
        for (int dd = 0; dd < 4; ++dd) {
            const float fv = (dd == 0) ? v.x : (dd == 1) ? v.y : (dd == 2) ? v.z : v.w;
            const float4* wr = (const float4*)(Ws + (q * 4 + dd) * 16);
            #pragma unroll
            for (int cq = 0; cq < 4; ++cq) {
                float4 wv = wr[cq];   // uniform addr -> broadcast b128
                acc[cq*4 + 0] += fv * wv.x;
                acc[cq*4 + 1] += fv * wv.y;
                acc[cq*4 + 2] += fv * wv.z;
                acc[cq*4 + 3] += fv * wv.w;
            }
        }
    }

    const float iv  = invn[row];
    const float mf  = (float)mask[row];
    const float nmf = 1.0f - mf;
    const float P100 = 2.6561398887587544e-5f;  // 0.9^100

    const int4* lr = (const int4*)(lab + (size_t)row * C_DIM);
    int li[16];
    #pragma unroll
    for (int g4 = 0; g4 < 4; ++g4) {
        int4 lv = lr[g4];
        li[g4*4 + 0] = lv.x; li[g4*4 + 1] = lv.y;
        li[g4*4 + 2] = lv.z; li[g4*4 + 3] = lv.w;
    }

    float p[16];
    #pragma unroll
    for (int c = 0; c < 16; ++c) {
        float lf  = (float)li[c];
        float upd = P100 * (lf * mf) + acc[c] * iv;   // 0.9^100 * p0 + D^-1 F W
        p[c] = upd * mf + lf * nmf;                   // literal mask arithmetic (NaN-faithful)
    }

    // numpy-compatible argmax: NaN treated as greatest, first occurrence wins
    float best = p[0];
    int idx = 0;
    #pragma unroll
    for (int c = 1; c < 16; ++c) {
        bool take = (p[c] > best) || ((p[c] != p[c]) && !(best != best));
        if (take) { best = p[c]; idx = c; }
    }
    out[row] = (float)idx;
}

extern "C" void kernel_launch(void* const* d_in, const int* in_sizes, int n_in,
                              void* d_out, int out_size, void* d_ws, size_t ws_size,
                              hipStream_t stream) {
    const float* F   = (const float*)d_in[0];
    const int* lab   = (const int*)d_in[1];
    const int* mask  = (const int*)d_in[2];
    float* ws   = (float*)d_ws;
    float* pH   = ws + WS_PH;
    float* pA   = ws + WS_PA;
    float* pR   = ws + WS_PR;
    float* invn = ws + WS_INVN;
    float* W    = ws + WS_W;
    float* Hf   = ws + WS_HF;
    float* Af   = ws + WS_AF;
    float* Rf   = ws + WS_RF;
    float* out  = (float*)d_out;

    lp_k1 <<<NBLK1, 256, 0, stream>>>(F, lab, mask, pH, pA, pR, invn);
    lp_k1b<<<24,    256, 0, stream>>>(pH, pA, pR, Hf, Af, Rf);
    lp_k2 <<<C_DIM,  64, 0, stream>>>(Hf, Af, Rf, W);
    lp_k3 <<<128,    64, 0, stream>>>(F, lab, mask, invn, W, out);
}

// Round 7
// 34.803 us; speedup vs baseline: 2.0250x; 2.0250x over previous
//
#include <hip/hip_runtime.h>
#include <math.h>

#define B_ROWS 8192
#define D_DIM 64
#define C_DIM 16
#define NBLK1 128
#define ROWS_PER_BLK 64    // 8192 / NBLK1
#define CHUNK 16

// ws layout (floats):
//   pH    : NBLK1 * 4096  = 524288
//   pA    : NBLK1 * 1024  = 131072
//   pR    : NBLK1 * 1024  = 131072
//   invn  : 8192
//   W     : 1024
//   Hfull : 4096
//   Afull : 1024
//   Rfull : 1024
#define WS_PH    0
#define WS_PA    524288
#define WS_PR    655360
#define WS_INVN  786432
#define WS_W     794624
#define WS_HF    795648
#define WS_AF    799744
#define WS_RF    800768

__global__ __launch_bounds__(256) void lp_k1(const float* __restrict__ F,
        const int* __restrict__ lab, const int* __restrict__ mask,
        float* __restrict__ pH, float* __restrict__ pA, float* __restrict__ pR,
        float* __restrict__ invn)
{
    __shared__ float cJ[ROWS_PER_BLK];                    // mask_j * (1/||f_j||)
    __shared__ __align__(16) float fbuf[CHUNK][D_DIM];
    __shared__ __align__(16) float labf[CHUNK][C_DIM];
    __shared__ float mflag[CHUNK];
    const int t = threadIdx.x;
    const int row0 = blockIdx.x * ROWS_PER_BLK;

    // phase 1: row norms (threads 0..63, one row each)
    if (t < ROWS_PER_BLK) {
        const float4* fr = (const float4*)(F + (size_t)(row0 + t) * D_DIM);
        float ss = 0.0f;
        #pragma unroll
        for (int q = 0; q < 16; ++q) {
            float4 v = fr[q];
            ss += v.x*v.x + v.y*v.y + v.z*v.z + v.w*v.w;
        }
        float iv = 1.0f / sqrtf(ss);
        invn[row0 + t] = iv;
        cJ[t] = mask[row0 + t] ? iv : 0.0f;
    }
    __syncthreads();

    // phase 2: accumulate partial H (64x64), A (64x16), r0 (64x16)
    float h[16];
    float aacc[4], racc[4];
    #pragma unroll
    for (int k = 0; k < 16; ++k) h[k] = 0.0f;
    #pragma unroll
    for (int j = 0; j < 4; ++j) { aacc[j] = 0.0f; racc[j] = 0.0f; }

    const int d1  = t >> 2;          // H row owned by this thread
    const int d2b = (t & 3) << 4;    // H col block base (16 cols)
    const int cb  = (t & 3) << 2;    // label quad base (4 cols)

    for (int ch = 0; ch < ROWS_PER_BLK / CHUNK; ++ch) {
        // stage F chunk: 256 float4, one per thread, fully coalesced
        ((float4*)fbuf)[t] =
            ((const float4*)(F + (size_t)(row0 + ch*CHUNK) * D_DIM))[t];
        // stage labels: 256 ints, one per thread
        ((float*)labf)[t] = (float)lab[(size_t)(row0 + ch*CHUNK) * C_DIM + t];
        if (t < CHUNK) mflag[t] = mask[row0 + ch*CHUNK + t] ? 1.0f : 0.0f;
        __syncthreads();

        #pragma unroll
        for (int r = 0; r < CHUNK; ++r) {
            const float coef = cJ[ch*CHUNK + r];      // uniform -> broadcast
            const float fraw = fbuf[r][d1];           // 16 distinct words -> no conflict
            const float fd1  = fraw * coef;
            const float4* frow = (const float4*)(&fbuf[r][d2b]);
            const float4 f0 = frow[0], f1 = frow[1], f2 = frow[2], f3 = frow[3];
            h[ 0] += fd1 * f0.x; h[ 1] += fd1 * f0.y; h[ 2] += fd1 * f0.z; h[ 3] += fd1 * f0.w;
            h[ 4] += fd1 * f1.x; h[ 5] += fd1 * f1.y; h[ 6] += fd1 * f1.z; h[ 7] += fd1 * f1.w;
            h[ 8] += fd1 * f2.x; h[ 9] += fd1 * f2.y; h[10] += fd1 * f2.z; h[11] += fd1 * f2.w;
            h[12] += fd1 * f3.x; h[13] += fd1 * f3.y; h[14] += fd1 * f3.z; h[15] += fd1 * f3.w;

            const float mf = mflag[r];                // uniform -> broadcast
            const float fm = fraw * mf;               // masked row coefficient
            const float fn = fraw - fm;               // (1-m) coefficient (m in {0,1} -> exact)
            const float4 lv = *(const float4*)(&labf[r][cb]);
            aacc[0] += fn * lv.x; aacc[1] += fn * lv.y; aacc[2] += fn * lv.z; aacc[3] += fn * lv.w;
            racc[0] += fm * lv.x; racc[1] += fm * lv.y; racc[2] += fm * lv.z; racc[3] += fm * lv.w;
        }
        __syncthreads();
    }

    // store layout: (t>>2)*64+(t&3)*16+k == t*16+k
    #pragma unroll
    for (int k = 0; k < 16; ++k)
        pH[(size_t)blockIdx.x * 4096 + t*16 + k] = h[k];
    #pragma unroll
    for (int j = 0; j < 4; ++j) {
        pA[(size_t)blockIdx.x * 1024 + t*4 + j] = aacc[j];
        pR[(size_t)blockIdx.x * 1024 + t*4 + j] = racc[j];
    }
}

// reduce the per-block partials -> Hfull (4096), Afull (1024), Rfull (1024)
// coalesced: thread e strides over b; fixed b order -> deterministic sums
__global__ __launch_bounds__(256) void lp_k1b(const float* __restrict__ pH,
        const float* __restrict__ pA, const float* __restrict__ pR,
        float* __restrict__ Hf, float* __restrict__ Af, float* __restrict__ Rf)
{
    const int e = blockIdx.x * 256 + threadIdx.x;   // 0..6143
    if (e < 4096) {
        float s = 0.0f;
        for (int b = 0; b < NBLK1; ++b) s += pH[(size_t)b * 4096 + e];
        Hf[e] = s;
    } else if (e < 5120) {
        const int i = e - 4096;
        float s = 0.0f;
        for (int b = 0; b < NBLK1; ++b) s += pA[(size_t)b * 1024 + i];
        Af[i] = s;
    } else {
        const int i = e - 5120;
        float s = 0.0f;
        for (int b = 0; b < NBLK1; ++b) s += pR[(size_t)b * 1024 + i];
        Rf[i] = s;
    }
}

// 16 independent column evolutions: block c, ONE wave, lane = d.
// H row in 64 VGPRs; no barriers/LDS in the loop — g broadcast via
// wave-synchronous v_readlane (compile-time lanes).
// NaN fixed-point early exit: once r and w are NaN in EVERY lane, each
// further iteration maps (r,w)->(NaN,NaN) exactly (g=r+a is NaN; the FMA
// reduction over 64 NaN-containing terms is NaN; 0.9*NaN+0.1*NaN is NaN),
// so breaking is bit-exact for ANY input, and deterministic in the inputs.
__global__ __launch_bounds__(64) void lp_k2(const float* __restrict__ Hf,
        const float* __restrict__ Af, const float* __restrict__ Rf,
        float* __restrict__ Wout)
{
    const int d = threadIdx.x;   // 0..63
    const int c = blockIdx.x;    // 0..15

    float4 hq[16];
    const float4* Hrow = (const float4*)(Hf + d * 64);
    #pragma unroll
    for (int q = 0; q < 16; ++q) hq[q] = Hrow[q];

    const float a = Af[d * 16 + c];
    float r = Rf[d * 16 + c];

    float w = 0.0f;
    float g = r;                 // g_0 = r_0 (no +a on iteration 0)
    #pragma unroll 1
    for (int it = 0; it < 100; ++it) {
        w = 0.9f * w + 0.1f * g;
        const int gb = __float_as_int(g);
        float acc0 = 0.f, acc1 = 0.f, acc2 = 0.f, acc3 = 0.f;
        #pragma unroll
        for (int q = 0; q < 16; ++q) {
            float g0 = __int_as_float(__builtin_amdgcn_readlane(gb, 4*q + 0));
            float g1 = __int_as_float(__builtin_amdgcn_readlane(gb, 4*q + 1));
            float g2 = __int_as_float(__builtin_amdgcn_readlane(gb, 4*q + 2));
            float g3 = __int_as_float(__builtin_amdgcn_readlane(gb, 4*q + 3));
            acc0 += hq[q].x * g0;
            acc1 += hq[q].y * g1;
            acc2 += hq[q].z * g2;
            acc3 += hq[q].w * g3;
        }
        r = 0.9f * r + 0.1f * ((acc0 + acc1) + (acc2 + acc3));
        g = r + a;               // g for next iteration (it>=1 includes +a)

        // exact NaN fixed-point convergence test (wave-uniform branch)
        if (__all((r != r) && (w != w))) break;
    }
    Wout[d * 16 + c] = w;
}

// one row per thread; q-loop NOT unrolled so only one 64-float Ws slice is
// live per scheduling region (prevents load-clustering -> VGPR spill)
__global__ __launch_bounds__(64) void lp_k3(const float* __restrict__ F,
        const int* __restrict__ lab, const int* __restrict__ mask,
        const float* __restrict__ invn, const float* __restrict__ Win,
        float* __restrict__ out)
{
    __shared__ __align__(16) float Ws[1024];   // [64][16] row-major
    const int t = threadIdx.x;                 // 0..63
    #pragma unroll
    for (int j = 0; j < 4; ++j)
        ((float4*)Ws)[j * 64 + t] = ((const float4*)Win)[j * 64 + t];
    __syncthreads();

    const int row = blockIdx.x * 64 + t;
    const float4* fr = (const float4*)(F + (size_t)row * D_DIM);

    float acc[16];
    #pragma unroll
    for (int c = 0; c < 16; ++c) acc[c] = 0.0f;

    #pragma unroll 1
    for (int q = 0; q < 16; ++q) {
        float4 v = fr[q];
        #pragma unroll
        for (int dd = 0; dd < 4; ++dd) {
            const float fv = (dd == 0) ? v.x : (dd == 1) ? v.y : (dd == 2) ? v.z : v.w;
            const float4* wr = (const float4*)(Ws + (q * 4 + dd) * 16);
            #pragma unroll
            for (int cq = 0; cq < 4; ++cq) {
                float4 wv = wr[cq];   // uniform addr -> broadcast b128
                acc[cq*4 + 0] += fv * wv.x;
                acc[cq*4 + 1] += fv * wv.y;
                acc[cq*4 + 2] += fv * wv.z;
                acc[cq*4 + 3] += fv * wv.w;
            }
        }
    }

    const float iv  = invn[row];
    const float mf  = (float)mask[row];
    const float nmf = 1.0f - mf;
    const float P100 = 2.6561398887587544e-5f;  // 0.9^100

    const int4* lr = (const int4*)(lab + (size_t)row * C_DIM);
    int li[16];
    #pragma unroll
    for (int g4 = 0; g4 < 4; ++g4) {
        int4 lv = lr[g4];
        li[g4*4 + 0] = lv.x; li[g4*4 + 1] = lv.y;
        li[g4*4 + 2] = lv.z; li[g4*4 + 3] = lv.w;
    }

    float p[16];
    #pragma unroll
    for (int c = 0; c < 16; ++c) {
        float lf  = (float)li[c];
        float upd = P100 * (lf * mf) + acc[c] * iv;   // 0.9^100 * p0 + D^-1 F W
        p[c] = upd * mf + lf * nmf;                   // literal mask arithmetic (NaN-faithful)
    }

    // numpy-compatible argmax: NaN treated as greatest, first occurrence wins
    float best = p[0];
    int idx = 0;
    #pragma unroll
    for (int c = 1; c < 16; ++c) {
        bool take = (p[c] > best) || ((p[c] != p[c]) && !(best != best));
        if (take) { best = p[c]; idx = c; }
    }
    out[row] = (float)idx;
}

extern "C" void kernel_launch(void* const* d_in, const int* in_sizes, int n_in,
                              void* d_out, int out_size, void* d_ws, size_t ws_size,
                              hipStream_t stream) {
    const float* F   = (const float*)d_in[0];
    const int* lab   = (const int*)d_in[1];
    const int* mask  = (const int*)d_in[2];
    float* ws   = (float*)d_ws;
    float* pH   = ws + WS_PH;
    float* pA   = ws + WS_PA;
    float* pR   = ws + WS_PR;
    float* invn = ws + WS_INVN;
    float* W    = ws + WS_W;
    float* Hf   = ws + WS_HF;
    float* Af   = ws + WS_AF;
    float* Rf   = ws + WS_RF;
    float* out  = (float*)d_out;

    lp_k1 <<<NBLK1, 256, 0, stream>>>(F, lab, mask, pH, pA, pR, invn);
    lp_k1b<<<24,    256, 0, stream>>>(pH, pA, pR, Hf, Af, Rf);
    lp_k2 <<<C_DIM,  64, 0, stream>>>(Hf, Af, Rf, W);
    lp_k3 <<<128,    64, 0, stream>>>(F, lab, mask, invn, W, out);
}